// Round 1
// baseline (1153.587 us; speedup 1.0000x reference)
//
#include <hip/hip_runtime.h>

#define NSAMP 4096
#define MDIM  7
#define KCH   128

// packed valid-row base per degree l: rows l*l .. l*l+2l  (total 16 rows)
static constexpr int RB[4] = {0, 1, 4, 9};

// CG paths in the exact Python enumeration order:
// for L in 0..3: for l1 in 0..3: for l2 in 0..3: if |l1-l2| <= L <= l1+l2
static constexpr int P_L1[34] = {0,1,2,3, 0,1,1,1,2,2,2,3,3, 0,1,1,1,2,2,2,2,3,3,3, 0,1,1,2,2,2,3,3,3,3};
static constexpr int P_L2[34] = {0,1,2,3, 1,0,1,2,1,2,3,2,3, 2,1,2,3,0,1,2,3,1,2,3, 3,2,3,1,2,3,0,1,2,3};
static constexpr int P_LO[34] = {0,0,0,0, 1,1,1,1,1,1,1,1,1, 2,2,2,2,2,2,2,2,2,2,2, 3,3,3,3,3,3,3,3,3,3};

// Channel mix: acc[r] += sum_k S[k][r] * W[l(r)][k][j]
// S is the per-sample LDS tile [128][20] (transposed, padded), W is [4][128][128].
__device__ __forceinline__ void mix_into(const float (*__restrict__ S)[20],
                                         const float* __restrict__ Wb,
                                         int j, float* acc)
{
#pragma unroll 4
    for (int k = 0; k < KCH; ++k) {
        const float4 x0 = *(const float4*)&S[k][0];
        const float4 x1 = *(const float4*)&S[k][4];
        const float4 x2 = *(const float4*)&S[k][8];
        const float4 x3 = *(const float4*)&S[k][12];
        const float w0 = Wb[(0 * KCH + k) * KCH + j];
        const float w1 = Wb[(1 * KCH + k) * KCH + j];
        const float w2 = Wb[(2 * KCH + k) * KCH + j];
        const float w3 = Wb[(3 * KCH + k) * KCH + j];
        acc[0]  += x0.x * w0;
        acc[1]  += x0.y * w1; acc[2]  += x0.z * w1; acc[3]  += x0.w * w1;
        acc[4]  += x1.x * w2; acc[5]  += x1.y * w2; acc[6]  += x1.z * w2; acc[7]  += x1.w * w2;
        acc[8]  += x2.x * w2;
        acc[9]  += x2.y * w3; acc[10] += x2.z * w3; acc[11] += x2.w * w3;
        acc[12] += x3.x * w3; acc[13] += x3.y * w3; acc[14] += x3.z * w3; acc[15] += x3.w * w3;
    }
}

__global__ __launch_bounds__(256) void cg_kernel(
    const float* __restrict__ feats,   // [4][4096][7][128]
    const float* __restrict__ U,       // [34][7][7][7]
    const float* __restrict__ mW,      // [3][4][128][128]
    const float* __restrict__ iW,      // [2][4][128][128]
    float* __restrict__ out)           // [4][4096][7][128]
{
    __shared__ __align__(16) float Ft[2][KCH][20];  // feats, transposed [k][row]
    __shared__ __align__(16) float Tt[2][KCH][20];  // tp bounce buffer

    const int tid = threadIdx.x;
    const int s = tid >> 7;          // sample within block (0/1)
    const int j = tid & 127;         // channel
    const int n = blockIdx.x * 2 + s;

    // ---- stage feats column j (16 valid rows) into LDS, transposed ----
    float fv[16];
#pragma unroll
    for (int l = 0; l < 4; ++l) {
#pragma unroll
        for (int m = 0; m < 2 * l + 1; ++m) {
            fv[RB[l] + m] = feats[(((size_t)l * NSAMP + n) * MDIM + m) * KCH + j];
        }
    }
#pragma unroll
    for (int q = 0; q < 4; ++q) {
        *(float4*)&Ft[s][j][4 * q] =
            make_float4(fv[4 * q], fv[4 * q + 1], fv[4 * q + 2], fv[4 * q + 3]);
    }
    __syncthreads();

    // ---- cur = spherical_linear(feats, mixer_W[0]) ----
    float cur[16];
#pragma unroll
    for (int r = 0; r < 16; ++r) cur[r] = 0.0f;
    mix_into(Ft[s], mW, j, cur);

    float mt[16], tp[16];

#pragma unroll 1
    for (int t = 0; t < 2; ++t) {
        // mt = spherical_linear(feats, mixer_W[t+1])
#pragma unroll
        for (int r = 0; r < 16; ++r) mt[r] = 0.0f;
        mix_into(Ft[s], mW + (size_t)(t + 1) * 4 * KCH * KCH, j, mt);

        // tp = tensor_product(cur, mt, U)   (elementwise in channel -> register local)
#pragma unroll
        for (int r = 0; r < 16; ++r) tp[r] = 0.0f;
#pragma unroll
        for (int p = 0; p < 34; ++p) {
            const int l1 = P_L1[p], l2 = P_L2[p], Lo = P_LO[p];
            const float* __restrict__ Up = U + p * 343;
#pragma unroll
            for (int a = 0; a < 2 * l1 + 1; ++a) {
#pragma unroll
                for (int b = 0; b < 2 * l2 + 1; ++b) {
                    const float prod = cur[RB[l1] + a] * mt[RB[l2] + b];
#pragma unroll
                    for (int c = 0; c < 2 * Lo + 1; ++c) {
                        tp[RB[Lo] + c] += prod * Up[(a * 7 + b) * 7 + c];
                    }
                }
            }
        }

        // stage tp into LDS (transposed), then cur += spherical_linear(tp, iter_W[t])
        __syncthreads();   // protect Tt from previous iteration's readers
#pragma unroll
        for (int q = 0; q < 4; ++q) {
            *(float4*)&Tt[s][j][4 * q] =
                make_float4(tp[4 * q], tp[4 * q + 1], tp[4 * q + 2], tp[4 * q + 3]);
        }
        __syncthreads();

        mix_into(Tt[s], iW + (size_t)t * 4 * KCH * KCH, j, cur);
    }

    // ---- write output, zero-filling invalid m rows ----
#pragma unroll
    for (int l = 0; l < 4; ++l) {
#pragma unroll
        for (int m = 0; m < 7; ++m) {
            const float v = (m < 2 * l + 1) ? cur[RB[l] + m] : 0.0f;
            out[(((size_t)l * NSAMP + n) * MDIM + m) * KCH + j] = v;
        }
    }
}

extern "C" void kernel_launch(void* const* d_in, const int* in_sizes, int n_in,
                              void* d_out, int out_size, void* d_ws, size_t ws_size,
                              hipStream_t stream)
{
    const float* feats = (const float*)d_in[0];
    const float* U     = (const float*)d_in[1];
    const float* mW    = (const float*)d_in[2];
    const float* iW    = (const float*)d_in[3];
    float* out = (float*)d_out;

    dim3 grid(NSAMP / 2);
    dim3 block(256);
    hipLaunchKernelGGL(cg_kernel, grid, block, 0, stream, feats, U, mW, iW, out);
}

// Round 2
// 984.219 us; speedup vs baseline: 1.1721x; 1.1721x over previous
//
#include <hip/hip_runtime.h>

#define NSAMP 4096
#define KCH   128
#define MDIM  7
#define TILE_N 4
#define NRT   6

typedef __attribute__((ext_vector_type(8))) short bf16x8;
typedef __attribute__((ext_vector_type(4))) float f32x4;

static constexpr int RB[4]      = {0, 1, 4, 9};
static constexpr int RT_L[NRT]  = {0, 1, 2, 2, 3, 3};
static constexpr int RT_I0[NRT] = {0, 0, 0, 16, 0, 16};
static constexpr int PR_L[16] = {0,1,1,1,2,2,2,2,2,3,3,3,3,3,3,3};
static constexpr int PR_M[16] = {0,0,1,2,0,1,2,3,4,0,1,2,3,4,5,6};

// CG paths in Python enumeration order
static constexpr int P_L1[34] = {0,1,2,3, 0,1,1,1,2,2,2,3,3, 0,1,1,1,2,2,2,2,3,3,3, 0,1,1,2,2,2,3,3,3,3};
static constexpr int P_L2[34] = {0,1,2,3, 1,0,1,2,1,2,3,2,3, 2,1,2,3,0,1,2,3,1,2,3, 3,2,3,1,2,3,0,1,2,3};
static constexpr int P_LO[34] = {0,0,0,0, 1,1,1,1,1,1,1,1,1, 2,2,2,2,2,2,2,2,2,2,2, 3,3,3,3,3,3,3,3,3,3};

static __device__ __forceinline__ unsigned short f2bf(float x) {
    unsigned u = __builtin_bit_cast(unsigned, x);
    u = u + 0x7FFFu + ((u >> 16) & 1u);
    return (unsigned short)(u >> 16);
}
static __device__ __forceinline__ float bf2f(unsigned short h) {
    unsigned u = ((unsigned)h) << 16;
    return __builtin_bit_cast(float, u);
}

// A-fragment read from a pre-split bf16 plane [row16][128], chunk-XOR swizzled.
static __device__ __forceinline__ bf16x8 ldA(const unsigned short* P, int row16, int ks, int kg) {
    int cs = (ks * 4 + kg) ^ (row16 & 7);
    return *(const bf16x8*)(P + row16 * 128 + cs * 8);
}

// ---------------- prep: W -> bf16 hi/lo in B-fragment order ----------------
__global__ __launch_bounds__(256) void cg_prep(const float* __restrict__ mW,
                                               const float* __restrict__ iW,
                                               unsigned short* __restrict__ Wp)
{
    int gid = blockIdx.x * 256 + threadIdx.x;       // 81920 total
    int lane = gid & 63;
    int set  = gid >> 6;                            // 1280 sets
    int spl = set & 1;
    int ks  = (set >> 1) & 3;
    int ct  = (set >> 3) & 7;
    int l   = (set >> 6) & 3;
    int mi  = set >> 8;                             // 0..4
    const float* src = (mi < 3) ? (mW + ((size_t)mi * 4 + l) * (KCH * KCH))
                                : (iW + ((size_t)(mi - 3) * 4 + l) * (KCH * KCH));
    int j  = ct * 16 + (lane & 15);
    int kb = ks * 32 + (lane >> 4) * 8;
    unsigned short o[8];
#pragma unroll
    for (int e = 0; e < 8; ++e) {
        float w = src[(size_t)(kb + e) * KCH + j];
        unsigned short h = f2bf(w);
        o[e] = spl ? f2bf(w - bf2f(h)) : h;
    }
    uint4 pk;
    unsigned* pw = (unsigned*)&pk;
#pragma unroll
    for (int q = 0; q < 4; ++q) pw[q] = (unsigned)o[2*q] | ((unsigned)o[2*q+1] << 16);
    *(uint4*)(Wp + (size_t)set * 512 + lane * 8) = pk;
}

// ---------------- TP path loop (register-local, unrolled) ----------------
static __device__ __forceinline__ void tensor_paths(const float* __restrict__ Uc,
                                                    const float* curv, const float* mtv,
                                                    float* tpv)
{
#pragma unroll
    for (int r = 0; r < 16; ++r) tpv[r] = 0.0f;
#pragma unroll
    for (int p = 0; p < 34; ++p) {
        const int l1 = P_L1[p], l2 = P_L2[p], Lo = P_LO[p];
        const float* __restrict__ Up = Uc + p * 343;
#pragma unroll
        for (int a = 0; a < 2 * l1 + 1; ++a) {
#pragma unroll
            for (int b = 0; b < 2 * l2 + 1; ++b) {
                const float prod = curv[RB[l1] + a] * mtv[RB[l2] + b];
#pragma unroll
                for (int c = 0; c < 2 * Lo + 1; ++c) {
                    tpv[RB[Lo] + c] += prod * Up[(a * 7 + b) * 7 + c];
                }
            }
        }
    }
}

// ---------------- mix pass (MFMA, hi/lo split) ----------------
template<int MI0, int MI1, bool DUAL>
static __device__ __forceinline__ void mix_pass(const unsigned short* Ah, const unsigned short* Al,
                                                const bf16x8* __restrict__ Wp, int ct, int lane,
                                                const int* r16, f32x4* acc, f32x4* macc)
{
    const int kg = lane >> 4;
#pragma unroll
    for (int ks = 0; ks < 4; ++ks) {
        bf16x8 ah[NRT], al[NRT];
#pragma unroll
        for (int rt = 0; rt < NRT; ++rt) {
            ah[rt] = ldA(Ah, r16[rt], ks, kg);
            al[rt] = ldA(Al, r16[rt], ks, kg);
        }
        bf16x8 bh[4], bl[4], ch[4], cl[4];
#pragma unroll
        for (int l = 0; l < 4; ++l) {
            const int s0 = (((MI0 * 4 + l) * 8 + ct) * 4 + ks) * 2;
            bh[l] = Wp[(size_t)s0 * 64 + lane];
            bl[l] = Wp[(size_t)(s0 + 1) * 64 + lane];
            if (DUAL) {
                const int s1 = (((MI1 * 4 + l) * 8 + ct) * 4 + ks) * 2;
                ch[l] = Wp[(size_t)s1 * 64 + lane];
                cl[l] = Wp[(size_t)(s1 + 1) * 64 + lane];
            }
        }
#pragma unroll
        for (int rt = 0; rt < NRT; ++rt)
            acc[rt] = __builtin_amdgcn_mfma_f32_16x16x32_bf16(ah[rt], bh[RT_L[rt]], acc[rt], 0, 0, 0);
#pragma unroll
        for (int rt = 0; rt < NRT; ++rt)
            acc[rt] = __builtin_amdgcn_mfma_f32_16x16x32_bf16(ah[rt], bl[RT_L[rt]], acc[rt], 0, 0, 0);
#pragma unroll
        for (int rt = 0; rt < NRT; ++rt)
            acc[rt] = __builtin_amdgcn_mfma_f32_16x16x32_bf16(al[rt], bh[RT_L[rt]], acc[rt], 0, 0, 0);
        if (DUAL) {
#pragma unroll
            for (int rt = 0; rt < NRT; ++rt)
                macc[rt] = __builtin_amdgcn_mfma_f32_16x16x32_bf16(ah[rt], ch[RT_L[rt]], macc[rt], 0, 0, 0);
#pragma unroll
            for (int rt = 0; rt < NRT; ++rt)
                macc[rt] = __builtin_amdgcn_mfma_f32_16x16x32_bf16(ah[rt], cl[RT_L[rt]], macc[rt], 0, 0, 0);
#pragma unroll
            for (int rt = 0; rt < NRT; ++rt)
                macc[rt] = __builtin_amdgcn_mfma_f32_16x16x32_bf16(al[rt], ch[RT_L[rt]], macc[rt], 0, 0, 0);
        }
    }
}

// acc (C-layout) -> f32 column buffer [n][j][16]
static __device__ __forceinline__ void store_acc(const f32x4* acc, float* dst, int ct, int lane)
{
    const int j   = ct * 16 + (lane & 15);
    const int rq0 = (lane >> 4) * 4;
#pragma unroll
    for (int rt = 0; rt < NRT; ++rt) {
        const int l = RT_L[rt], ml = 2 * l + 1, nv = TILE_N * ml;
#pragma unroll
        for (int q = 0; q < 4; ++q) {
            const int idx = RT_I0[rt] + rq0 + q;
            if (idx < nv) {
                const int nn = idx / ml;
                const int m  = idx - nn * ml;
                dst[((nn * KCH + j) << 4) + RB[l] + m] = acc[rt][q];
            }
        }
    }
}

// ---------------- main fused kernel ----------------
__global__ __launch_bounds__(512, 2) void cg_main(const float* __restrict__ feats,
                                                  const float* __restrict__ Uc,
                                                  const bf16x8* __restrict__ Wp,
                                                  float* __restrict__ out)
{
    extern __shared__ char smem[];
    unsigned short* Fh = (unsigned short*)smem;            // 16 KB
    unsigned short* Fl = Fh + 8192;                        // 16 KB
    unsigned short* Th = Fl + 8192;                        // 16 KB
    unsigned short* Tl = Th + 8192;                        // 16 KB
    float* Cur = (float*)(smem + 65536);                   // 32 KB
    float* Mt  = Cur + 8192;                               // 32 KB

    const int tid  = threadIdx.x;
    const int lane = tid & 63;
    const int ct   = tid >> 6;           // wave id = output col-tile
    const int n0   = blockIdx.x * TILE_N;

    // ---- stage feats -> Fh/Fl (pre-split bf16, compact [row16][128], XOR-swizzled) ----
    {
        const int row16 = tid >> 3;              // 0..63
        const int k0    = (tid & 7) * 16;        // 16 floats per thread
        const int pr = row16 & 15, nn = row16 >> 4;
        const int l = PR_L[pr], m = PR_M[pr];
        const float* g = feats + (((size_t)l * NSAMP + n0 + nn) * MDIM + m) * KCH + k0;
        float v[16];
#pragma unroll
        for (int q = 0; q < 4; ++q) {
            f32x4 t = *(const f32x4*)(g + 4 * q);
            v[4*q] = t[0]; v[4*q+1] = t[1]; v[4*q+2] = t[2]; v[4*q+3] = t[3];
        }
        unsigned short hi[16], lo[16];
#pragma unroll
        for (int i = 0; i < 16; ++i) {
            hi[i] = f2bf(v[i]);
            lo[i] = f2bf(v[i] - bf2f(hi[i]));
        }
#pragma unroll
        for (int c2 = 0; c2 < 2; ++c2) {
            const int c  = (k0 >> 3) + c2;
            const int cs = c ^ (row16 & 7);
            uint4 ph, pl;
            unsigned* pwh = (unsigned*)&ph;
            unsigned* pwl = (unsigned*)&pl;
#pragma unroll
            for (int q = 0; q < 4; ++q) {
                pwh[q] = (unsigned)hi[c2*8 + 2*q] | ((unsigned)hi[c2*8 + 2*q + 1] << 16);
                pwl[q] = (unsigned)lo[c2*8 + 2*q] | ((unsigned)lo[c2*8 + 2*q + 1] << 16);
            }
            *(uint4*)(Fh + row16 * 128 + cs * 8) = ph;
            *(uint4*)(Fl + row16 * 128 + cs * 8) = pl;
        }
    }

    // per-lane A-row map for each row-tile (invalid rows clamped -> garbage confined)
    int r16[NRT];
#pragma unroll
    for (int rt = 0; rt < NRT; ++rt) {
        const int l = RT_L[rt], ml = 2 * l + 1, nv = TILE_N * ml;
        int idx = RT_I0[rt] + (lane & 15);
        idx = idx < nv ? idx : nv - 1;
        const int nn = idx / ml;
        const int m  = idx - nn * ml;
        r16[rt] = nn * 16 + RB[l] + m;
    }

    __syncthreads();

    f32x4 acc[NRT], macc[NRT];
#pragma unroll
    for (int rt = 0; rt < NRT; ++rt) {
        acc[rt][0] = acc[rt][1] = acc[rt][2] = acc[rt][3] = 0.0f;
        macc[rt][0] = macc[rt][1] = macc[rt][2] = macc[rt][3] = 0.0f;
    }

    // cur = mix(feats, mW0); mt = mix(feats, mW1)   (dual pass shares A-frags)
    mix_pass<0, 1, true>(Fh, Fl, Wp, ct, lane, r16, acc, macc);
    store_acc(acc,  Cur, ct, lane);
    store_acc(macc, Mt,  ct, lane);
    __syncthreads();

    const int tn = tid >> 7;        // TP task: sample
    const int tj = tid & 127;       // TP task: channel
    const float* cp = Cur + ((tn * KCH + tj) << 4);
    const float* mp = Mt  + ((tn * KCH + tj) << 4);

    // ---------------- t = 0 ----------------
    {
        float curv[16], mtv[16], tpv[16];
#pragma unroll
        for (int q = 0; q < 4; ++q) {
            f32x4 a = *(const f32x4*)(cp + 4 * q);
            f32x4 b = *(const f32x4*)(mp + 4 * q);
            curv[4*q] = a[0]; curv[4*q+1] = a[1]; curv[4*q+2] = a[2]; curv[4*q+3] = a[3];
            mtv[4*q]  = b[0]; mtv[4*q+1]  = b[1]; mtv[4*q+2]  = b[2]; mtv[4*q+3]  = b[3];
        }
        tensor_paths(Uc, curv, mtv, tpv);
#pragma unroll
        for (int pr = 0; pr < 16; ++pr) {
            const int row16 = tn * 16 + pr;
            const int cs = (tj >> 3) ^ (row16 & 7);
            const int idx = row16 * 128 + cs * 8 + (tj & 7);
            unsigned short h = f2bf(tpv[pr]);
            Th[idx] = h;
            Tl[idx] = f2bf(tpv[pr] - bf2f(h));
        }
    }
    __syncthreads();

    // cur += mix(tp, iW0);  mt = mix(feats, mW2)
#pragma unroll
    for (int rt = 0; rt < NRT; ++rt)
        macc[rt][0] = macc[rt][1] = macc[rt][2] = macc[rt][3] = 0.0f;
    mix_pass<3, 0, false>(Th, Tl, Wp, ct, lane, r16, acc, nullptr);
    mix_pass<2, 0, false>(Fh, Fl, Wp, ct, lane, r16, macc, nullptr);
    store_acc(acc,  Cur, ct, lane);
    store_acc(macc, Mt,  ct, lane);
    __syncthreads();

    // ---------------- t = 1 ----------------
    {
        float curv[16], mtv[16], tpv[16];
#pragma unroll
        for (int q = 0; q < 4; ++q) {
            f32x4 a = *(const f32x4*)(cp + 4 * q);
            f32x4 b = *(const f32x4*)(mp + 4 * q);
            curv[4*q] = a[0]; curv[4*q+1] = a[1]; curv[4*q+2] = a[2]; curv[4*q+3] = a[3];
            mtv[4*q]  = b[0]; mtv[4*q+1]  = b[1]; mtv[4*q+2]  = b[2]; mtv[4*q+3]  = b[3];
        }
        tensor_paths(Uc, curv, mtv, tpv);
#pragma unroll
        for (int pr = 0; pr < 16; ++pr) {
            const int row16 = tn * 16 + pr;
            const int cs = (tj >> 3) ^ (row16 & 7);
            const int idx = row16 * 128 + cs * 8 + (tj & 7);
            unsigned short h = f2bf(tpv[pr]);
            Th[idx] = h;
            Tl[idx] = f2bf(tpv[pr] - bf2f(h));
        }
    }
    __syncthreads();

    // cur += mix(tp, iW1)
    mix_pass<4, 0, false>(Th, Tl, Wp, ct, lane, r16, acc, nullptr);
    store_acc(acc, Cur, ct, lane);
    __syncthreads();

    // ---- output: read Cur columns, zero-fill invalid m ----
    {
        const float* c = Cur + ((tn * KCH + tj) << 4);
#pragma unroll
        for (int l = 0; l < 4; ++l) {
#pragma unroll
            for (int m = 0; m < 7; ++m) {
                const float v = (m < 2 * l + 1) ? c[RB[l] + m] : 0.0f;
                out[(((size_t)l * NSAMP + n0 + tn) * MDIM + m) * KCH + tj] = v;
            }
        }
    }
}

extern "C" void kernel_launch(void* const* d_in, const int* in_sizes, int n_in,
                              void* d_out, int out_size, void* d_ws, size_t ws_size,
                              hipStream_t stream)
{
    const float* feats = (const float*)d_in[0];
    const float* U     = (const float*)d_in[1];
    const float* mW    = (const float*)d_in[2];
    const float* iW    = (const float*)d_in[3];
    float* out = (float*)d_out;

    hipFuncSetAttribute(reinterpret_cast<const void*>(cg_prep),
                        hipFuncAttributeMaxDynamicSharedMemorySize, 0);
    hipFuncSetAttribute(reinterpret_cast<const void*>(cg_main),
                        hipFuncAttributeMaxDynamicSharedMemorySize, 131072);

    cg_prep<<<320, 256, 0, stream>>>(mW, iW, (unsigned short*)d_ws);
    cg_main<<<NSAMP / TILE_N, 512, 131072, stream>>>(feats, U, (const bf16x8*)d_ws, out);
}

// Round 4
// 486.077 us; speedup vs baseline: 2.3733x; 2.0248x over previous
//
#include <hip/hip_runtime.h>

#define NSAMP 4096
#define KCH   128
#define MDIM  7

typedef __attribute__((ext_vector_type(8))) short bf16x8;
typedef __attribute__((ext_vector_type(4))) float f32x4;

static constexpr int RB[4] = {0, 1, 4, 9};
static constexpr int RE[4] = {1, 4, 9, 16};
static constexpr int PR_L[16] = {0,1,1,1,2,2,2,2,2,3,3,3,3,3,3,3};
static constexpr int PR_M[16] = {0,0,1,2,0,1,2,3,4,0,1,2,3,4,5,6};

// CG paths in Python enumeration order
static constexpr int P_L1[34] = {0,1,2,3, 0,1,1,1,2,2,2,3,3, 0,1,1,1,2,2,2,2,3,3,3, 0,1,1,2,2,2,3,3,3,3};
static constexpr int P_L2[34] = {0,1,2,3, 1,0,1,2,1,2,3,2,3, 2,1,2,3,0,1,2,3,1,2,3, 3,2,3,1,2,3,0,1,2,3};
static constexpr int P_LO[34] = {0,0,0,0, 1,1,1,1,1,1,1,1,1, 2,2,2,2,2,2,2,2,2,2,2, 3,3,3,3,3,3,3,3,3,3};

// invalid (l,m) rows for zero-fill
static constexpr int ZL[12] = {0,0,0,0,0,0, 1,1,1,1, 2,2};
static constexpr int ZM[12] = {1,2,3,4,5,6, 3,4,5,6, 5,6};

#define WP_BYTES 1310720u   // 1280 sets * 512 shorts * 2B

static __device__ __forceinline__ unsigned short f2bf(float x) {
    unsigned u = __builtin_bit_cast(unsigned, x);
    u = u + 0x7FFFu + ((u >> 16) & 1u);
    return (unsigned short)(u >> 16);
}
static __device__ __forceinline__ float bf2f(unsigned short h) {
    unsigned u = ((unsigned)h) << 16;
    return __builtin_bit_cast(float, u);
}

// ---------------- K0: W -> bf16 hi/lo in B-fragment order (R2-proven) ----------------
__global__ __launch_bounds__(256) void cg_prep(const float* __restrict__ mW,
                                               const float* __restrict__ iW,
                                               unsigned short* __restrict__ Wp)
{
    int gid = blockIdx.x * 256 + threadIdx.x;
    int lane = gid & 63;
    int set  = gid >> 6;                            // 1280 sets
    int spl = set & 1;
    int ks  = (set >> 1) & 3;
    int ct  = (set >> 3) & 7;
    int l   = (set >> 6) & 3;
    int mi  = set >> 8;                             // 0..4
    const float* src = (mi < 3) ? (mW + ((size_t)mi * 4 + l) * (KCH * KCH))
                                : (iW + ((size_t)(mi - 3) * 4 + l) * (KCH * KCH));
    int j  = ct * 16 + (lane & 15);
    int kb = ks * 32 + (lane >> 4) * 8;
    unsigned short o[8];
#pragma unroll
    for (int e = 0; e < 8; ++e) {
        float w = src[(size_t)(kb + e) * KCH + j];
        unsigned short h = f2bf(w);
        o[e] = spl ? f2bf(w - bf2f(h)) : h;
    }
    uint4 pk;
    unsigned* pw = (unsigned*)&pk;
#pragma unroll
    for (int q = 0; q < 4; ++q) pw[q] = (unsigned)o[2*q] | ((unsigned)o[2*q+1] << 16);
    *(uint4*)(Wp + (size_t)set * 512 + lane * 8) = pk;
}

// A-fragment read from bf16 plane [256 rows][128], chunk-XOR swizzled by (key&7)
static __device__ __forceinline__ bf16x8 ldF(const unsigned short* P, int row16, int key, int c) {
    int cs = c ^ (key & 7);
    return *(const bf16x8*)(P + row16 * 128 + cs * 8);
}

// ---------------- K2: three mixer GEMMs, rows = samples ----------------
__global__ __launch_bounds__(512, 2) void cg_mix3(const float* __restrict__ feats,
                                                  const bf16x8* __restrict__ Wp,
                                                  float* __restrict__ P0,
                                                  float* __restrict__ P1,
                                                  float* __restrict__ P2,
                                                  int base)
{
    extern __shared__ char smem[];
    unsigned short* Fh = (unsigned short*)smem;            // 64 KB: [256 rows][128]
    unsigned short* Fl = Fh + 32768;                       // 64 KB

    const int tid  = threadIdx.x;
    const int lane = tid & 63;
    const int ct   = tid >> 6;              // wave id = j col-tile
    const int nl0  = blockIdx.x * 16;       // chunk-local sample base

    // ---- stage feats -> hi/lo bf16 LDS, rows (r,n), XOR-swizzled chunks ----
    {
        const int row = tid >> 1;           // 0..255 = r*16 + nlr
        const int r   = row >> 4;
        const int nlr = row & 15;
        const int kh  = tid & 1;
        const int l = PR_L[r], m = PR_M[r];
        const float* g = feats + (((size_t)l * NSAMP + (base + nl0 + nlr)) * MDIM + m) * KCH + kh * 64;
        unsigned short* fh = Fh + row * 128;
        unsigned short* fl = Fl + row * 128;
#pragma unroll
        for (int c8 = 0; c8 < 8; ++c8) {
            f32x4 a = *(const f32x4*)(g + c8 * 8);
            f32x4 b = *(const f32x4*)(g + c8 * 8 + 4);
            float v[8] = {a[0], a[1], a[2], a[3], b[0], b[1], b[2], b[3]};
            unsigned short hi[8], lo[8];
#pragma unroll
            for (int i = 0; i < 8; ++i) {
                hi[i] = f2bf(v[i]);
                lo[i] = f2bf(v[i] - bf2f(hi[i]));
            }
            uint4 ph, pl;
            unsigned* pwh = (unsigned*)&ph;
            unsigned* pwl = (unsigned*)&pl;
#pragma unroll
            for (int q = 0; q < 4; ++q) {
                pwh[q] = (unsigned)hi[2*q] | ((unsigned)hi[2*q+1] << 16);
                pwl[q] = (unsigned)lo[2*q] | ((unsigned)lo[2*q+1] << 16);
            }
            const int cs = (kh * 8 + c8) ^ (nlr & 7);
            *(uint4*)(fh + cs * 8) = ph;
            *(uint4*)(fl + cs * 8) = pl;
        }
    }
    __syncthreads();

    const int kg = lane >> 4;
    const int l15 = lane & 15;
    const int j = ct * 16 + l15;

    // ---- dual sweep: mi = 0 and 1 ----
    f32x4 acc0[16], acc1[16];
#pragma unroll
    for (int r = 0; r < 16; ++r) {
        acc0[r][0]=acc0[r][1]=acc0[r][2]=acc0[r][3]=0.0f;
        acc1[r][0]=acc1[r][1]=acc1[r][2]=acc1[r][3]=0.0f;
    }
#pragma unroll
    for (int ks = 0; ks < 4; ++ks) {
#pragma unroll
        for (int l = 0; l < 4; ++l) {
            const int s0 = (((0 * 4 + l) * 8 + ct) * 4 + ks) * 2;
            const int s1 = (((1 * 4 + l) * 8 + ct) * 4 + ks) * 2;
            bf16x8 b0h = Wp[(size_t)s0 * 64 + lane];
            bf16x8 b0l = Wp[(size_t)(s0 + 1) * 64 + lane];
            bf16x8 b1h = Wp[(size_t)s1 * 64 + lane];
            bf16x8 b1l = Wp[(size_t)(s1 + 1) * 64 + lane];
#pragma unroll
            for (int r = RB[l]; r < RE[l]; ++r) {
                bf16x8 ah = ldF(Fh, r * 16 + l15, l15, ks * 4 + kg);
                bf16x8 al = ldF(Fl, r * 16 + l15, l15, ks * 4 + kg);
                acc0[r] = __builtin_amdgcn_mfma_f32_16x16x32_bf16(ah, b0h, acc0[r], 0, 0, 0);
                acc0[r] = __builtin_amdgcn_mfma_f32_16x16x32_bf16(ah, b0l, acc0[r], 0, 0, 0);
                acc0[r] = __builtin_amdgcn_mfma_f32_16x16x32_bf16(al, b0h, acc0[r], 0, 0, 0);
                acc1[r] = __builtin_amdgcn_mfma_f32_16x16x32_bf16(ah, b1h, acc1[r], 0, 0, 0);
                acc1[r] = __builtin_amdgcn_mfma_f32_16x16x32_bf16(ah, b1l, acc1[r], 0, 0, 0);
                acc1[r] = __builtin_amdgcn_mfma_f32_16x16x32_bf16(al, b1h, acc1[r], 0, 0, 0);
            }
        }
    }
#pragma unroll
    for (int r = 0; r < 16; ++r) {
#pragma unroll
        for (int q = 0; q < 4; ++q) {
            const int nl = nl0 + (lane >> 4) * 4 + q;
            P0[((size_t)nl * 16 + r) * KCH + j] = acc0[r][q];
            P1[((size_t)nl * 16 + r) * KCH + j] = acc1[r][q];
        }
    }

    // ---- single sweep: mi = 2 ----
#pragma unroll
    for (int r = 0; r < 16; ++r) { acc0[r][0]=acc0[r][1]=acc0[r][2]=acc0[r][3]=0.0f; }
#pragma unroll
    for (int ks = 0; ks < 4; ++ks) {
#pragma unroll
        for (int l = 0; l < 4; ++l) {
            const int s0 = (((2 * 4 + l) * 8 + ct) * 4 + ks) * 2;
            bf16x8 bh = Wp[(size_t)s0 * 64 + lane];
            bf16x8 bl = Wp[(size_t)(s0 + 1) * 64 + lane];
#pragma unroll
            for (int r = RB[l]; r < RE[l]; ++r) {
                bf16x8 ah = ldF(Fh, r * 16 + l15, l15, ks * 4 + kg);
                bf16x8 al = ldF(Fl, r * 16 + l15, l15, ks * 4 + kg);
                acc0[r] = __builtin_amdgcn_mfma_f32_16x16x32_bf16(ah, bh, acc0[r], 0, 0, 0);
                acc0[r] = __builtin_amdgcn_mfma_f32_16x16x32_bf16(ah, bl, acc0[r], 0, 0, 0);
                acc0[r] = __builtin_amdgcn_mfma_f32_16x16x32_bf16(al, bh, acc0[r], 0, 0, 0);
            }
        }
    }
#pragma unroll
    for (int r = 0; r < 16; ++r) {
#pragma unroll
        for (int q = 0; q < 4; ++q) {
            const int nl = nl0 + (lane >> 4) * 4 + q;
            P2[((size_t)nl * 16 + r) * KCH + j] = acc0[r][q];
        }
    }
}

// ---------------- K3: tensor product, per-thread (n,k) ----------------
__global__ __launch_bounds__(256, 4) void cg_tp(const float* __restrict__ Pc,
                                                const float* __restrict__ Pm,
                                                unsigned short* __restrict__ TPH,
                                                unsigned short* __restrict__ TPL,
                                                const float* __restrict__ Uc)
{
    const int tid = threadIdx.x;
    const int nl = blockIdx.x * 2 + (tid >> 7);
    const int tj = tid & 127;

    float curv[16], mtv[16], tpv[16];
#pragma unroll
    for (int r = 0; r < 16; ++r) {
        curv[r] = Pc[((size_t)nl * 16 + r) * KCH + tj];
        mtv[r]  = Pm[((size_t)nl * 16 + r) * KCH + tj];
    }
#pragma unroll
    for (int r = 0; r < 16; ++r) tpv[r] = 0.0f;
#pragma unroll
    for (int p = 0; p < 34; ++p) {
        const int l1 = P_L1[p], l2 = P_L2[p], Lo = P_LO[p];
        const float* __restrict__ Up = Uc + p * 343;
#pragma unroll
        for (int a = 0; a < 2 * l1 + 1; ++a) {
#pragma unroll
            for (int b = 0; b < 2 * l2 + 1; ++b) {
                const float prod = curv[RB[l1] + a] * mtv[RB[l2] + b];
#pragma unroll
                for (int c = 0; c < 2 * Lo + 1; ++c) {
                    tpv[RB[Lo] + c] += prod * Up[(a * 7 + b) * 7 + c];
                }
            }
        }
    }
    // write tp hi/lo, pre-swizzled chunk layout keyed by (nl&7)
#pragma unroll
    for (int r = 0; r < 16; ++r) {
        const size_t addr = ((size_t)nl * 16 + r) * KCH + (size_t)(((tj >> 3) ^ (nl & 7)) * 8 + (tj & 7));
        unsigned short h = f2bf(tpv[r]);
        TPH[addr] = h;
        TPL[addr] = f2bf(tpv[r] - bf2f(h));
    }
}

// ---------------- K4: iter mix + residual (T=0 -> Pout, T=1 -> final out) ----------------
template<int T>
__global__ __launch_bounds__(512, 2) void cg_iter(const unsigned short* __restrict__ TPH,
                                                  const unsigned short* __restrict__ TPL,
                                                  const bf16x8* __restrict__ Wp,
                                                  const float* __restrict__ Pres,
                                                  float* __restrict__ Pout,
                                                  float* __restrict__ gout,
                                                  int base)
{
    extern __shared__ char smem[];
    unsigned short* Th = (unsigned short*)smem;   // 64 KB
    unsigned short* Tl = Th + 32768;              // 64 KB

    const int tid  = threadIdx.x;
    const int lane = tid & 63;
    const int ct   = tid >> 6;
    const int nl0  = blockIdx.x * 16;

    // linear LDS stage of this block's tp region (64 KB per plane)
    {
        const uint4* sh = (const uint4*)(TPH + (size_t)blockIdx.x * 32768);
        const uint4* sl = (const uint4*)(TPL + (size_t)blockIdx.x * 32768);
        uint4* dh = (uint4*)Th;
        uint4* dl = (uint4*)Tl;
#pragma unroll
        for (int it = 0; it < 8; ++it) {
            const int idx = it * 512 + tid;
            dh[idx] = sh[idx];
            dl[idx] = sl[idx];
        }
    }
    __syncthreads();

    const int kg = lane >> 4;
    const int l15 = lane & 15;
    const int j = ct * 16 + l15;

    f32x4 acc[16];
#pragma unroll
    for (int r = 0; r < 16; ++r) { acc[r][0]=acc[r][1]=acc[r][2]=acc[r][3]=0.0f; }

#pragma unroll
    for (int ks = 0; ks < 4; ++ks) {
#pragma unroll
        for (int l = 0; l < 4; ++l) {
            const int s0 = ((((3 + T) * 4 + l) * 8 + ct) * 4 + ks) * 2;
            bf16x8 bh = Wp[(size_t)s0 * 64 + lane];
            bf16x8 bl = Wp[(size_t)(s0 + 1) * 64 + lane];
#pragma unroll
            for (int r = RB[l]; r < RE[l]; ++r) {
                // rows of tp plane are nl*16 + r, swizzle key = nl&7
                bf16x8 ah = ldF(Th, l15 * 16 + r, l15, ks * 4 + kg);
                bf16x8 al = ldF(Tl, l15 * 16 + r, l15, ks * 4 + kg);
                acc[r] = __builtin_amdgcn_mfma_f32_16x16x32_bf16(ah, bh, acc[r], 0, 0, 0);
                acc[r] = __builtin_amdgcn_mfma_f32_16x16x32_bf16(ah, bl, acc[r], 0, 0, 0);
                acc[r] = __builtin_amdgcn_mfma_f32_16x16x32_bf16(al, bh, acc[r], 0, 0, 0);
            }
        }
    }

#pragma unroll
    for (int r = 0; r < 16; ++r) {
#pragma unroll
        for (int q = 0; q < 4; ++q) {
            const int nl = nl0 + (lane >> 4) * 4 + q;
            const float val = acc[r][q] + Pres[((size_t)nl * 16 + r) * KCH + j];
            if (T == 0) {
                Pout[((size_t)nl * 16 + r) * KCH + j] = val;
            } else {
                const int n = base + nl;
                gout[(((size_t)PR_L[r] * NSAMP + n) * MDIM + PR_M[r]) * KCH + j] = val;
            }
        }
    }

    if (T == 1) {
        // zero-fill the 12 invalid (l,m) rows
        const int j2 = tid & 127;
        const int g  = tid >> 7;     // 0..3
#pragma unroll
        for (int z = 0; z < 12; ++z) {
#pragma unroll
            for (int i = 0; i < 4; ++i) {
                const int n = base + nl0 + g * 4 + i;
                gout[(((size_t)ZL[z] * NSAMP + n) * MDIM + ZM[z]) * KCH + j2] = 0.0f;
            }
        }
    }
}

extern "C" void kernel_launch(void* const* d_in, const int* in_sizes, int n_in,
                              void* d_out, int out_size, void* d_ws, size_t ws_size,
                              hipStream_t stream)
{
    const float* feats = (const float*)d_in[0];
    const float* U     = (const float*)d_in[1];
    const float* mW    = (const float*)d_in[2];
    const float* iW    = (const float*)d_in[3];
    float* out = (float*)d_out;

    // chunk size by workspace: per-sample = 3*8192 (f32 P) + 2*4096 (bf16 tp) = 32768 B
    size_t avail = (ws_size > WP_BYTES) ? (ws_size - WP_BYTES) : 0;
    int NC = (int)(avail / 32768);
    NC = (NC / 16) * 16;
    if (NC > NSAMP) NC = NSAMP;
    if (NC < 16) return;   // workspace too small to run safely (not observed; R2 used 1.31MB+ fine)

    char* wsb = (char*)d_ws;
    unsigned short* Wp = (unsigned short*)wsb;
    float* P0 = (float*)(wsb + WP_BYTES);
    float* P1 = P0 + (size_t)NC * 2048;
    float* P2 = P1 + (size_t)NC * 2048;
    unsigned short* TPH = (unsigned short*)(P2 + (size_t)NC * 2048);
    unsigned short* TPL = TPH + (size_t)NC * 2048;

    hipFuncSetAttribute(reinterpret_cast<const void*>(cg_mix3),
                        hipFuncAttributeMaxDynamicSharedMemorySize, 131072);
    hipFuncSetAttribute(reinterpret_cast<const void*>(cg_iter<0>),
                        hipFuncAttributeMaxDynamicSharedMemorySize, 131072);
    hipFuncSetAttribute(reinterpret_cast<const void*>(cg_iter<1>),
                        hipFuncAttributeMaxDynamicSharedMemorySize, 131072);

    cg_prep<<<320, 256, 0, stream>>>(mW, iW, Wp);

    for (int base = 0; base < NSAMP; base += NC) {
        const int nc = (NSAMP - base < NC) ? (NSAMP - base) : NC;
        cg_mix3<<<nc / 16, 512, 131072, stream>>>(feats, (const bf16x8*)Wp, P0, P1, P2, base);
        cg_tp<<<nc / 2, 256, 0, stream>>>(P0, P1, TPH, TPL, U);
        cg_iter<0><<<nc / 16, 512, 131072, stream>>>(TPH, TPL, (const bf16x8*)Wp, P0, P1, nullptr, base);
        cg_tp<<<nc / 2, 256, 0, stream>>>(P1, P2, TPH, TPL, U);
        cg_iter<1><<<nc / 16, 512, 131072, stream>>>(TPH, TPL, (const bf16x8*)Wp, P1, nullptr, out, base);
    }
}